// Round 8
// baseline (228.368 us; speedup 1.0000x reference)
//
#include <hip/hip_runtime.h>

// YOLO-v1 loss, S=14, B=2, C=20, NCH=30, Nb=4096.
// R9: six structurally different kernels (R2..R8: staged/direct/pinned/
// counted-vmcnt/no-barrier) ALL land 72-83us. The invariant: WRITE_SIZE
// 104-200 MB on a kernel that writes 25 KB -- the harness restore leaves
// ~200MB dirty in L2/L3 (385MB working set > 256MB L3), and our miss-fills
// evict it. Kernel window = 94MB fetch + ~200MB writeback = 4.1 TB/s mixed,
// i.e. HBM-bound on hidden writeback traffic. Fix: NON-TEMPORAL loads
// (no allocate on miss -> no evictions -> dirty lines get overwritten in
// place by the next restore, never written back). Each byte is read once,
// so allocation was worthless anyway. Structure = R5 (known-correct direct
// loads), all loads via __builtin_nontemporal_load.

#define S_GRID 14
#define NB 4096
#define NCELL (NB * S_GRID * S_GRID)   // 802816 = 3136 * 256
#define NCH 30
#define CELLS_PER_BLOCK 256
#define NBLOCKS (NCELL / CELLS_PER_BLOCK)   // 3136

typedef float vf2 __attribute__((ext_vector_type(2)));

__global__ __launch_bounds__(256) void yolo_loss_partial(
    const float* __restrict__ pred, const float* __restrict__ target,
    float* __restrict__ partial)
{
    const int cell = blockIdx.x * CELLS_PER_BLOCK + threadIdx.x;  // exact grid
    const vf2* __restrict__ p2 = (const vf2*)(pred + (size_t)cell * NCH);
    const vf2* __restrict__ t2 = (const vf2*)(target + (size_t)cell * NCH);

    // Box channels 0..9 (vf2 indices 0..4), 8B-aligned (cell*120 % 8 == 0).
    // All loads non-temporal: no L2/L3 allocation on miss.
    float p[10], t[10];
#pragma unroll
    for (int i = 0; i < 5; ++i) {
        vf2 a = __builtin_nontemporal_load(p2 + i);
        p[2 * i] = a.x; p[2 * i + 1] = a.y;
        vf2 b = __builtin_nontemporal_load(t2 + i);
        t[2 * i] = b.x; t[2 * i + 1] = b.y;
    }

    const float t4 = t[4];
    const bool obj = (t4 > 0.0f);

    // no-object confidence loss over both box slots
    float dn0 = p[4] - t[4];
    float dn1 = p[9] - t[9];
    float noobj_l = (t4 == 0.0f) ? (dn0 * dn0 + dn1 * dn1) : 0.0f;

    // target box (slot 0) corners
    const float invS = 1.0f / 14.0f;
    float tcx = t[0] * invS, tcy = t[1] * invS;
    float tx1 = tcx - 0.5f * t[2], ty1 = tcy - 0.5f * t[3];
    float tx2 = tcx + 0.5f * t[2], ty2 = tcy + 0.5f * t[3];
    float area_t = (tx2 - tx1) * (ty2 - ty1);

    float iou[2];
#pragma unroll
    for (int b = 0; b < 2; ++b) {
        const float* pb = p + 5 * b;
        float cx = pb[0] * invS, cy = pb[1] * invS;
        float x1 = cx - 0.5f * pb[2], y1 = cy - 0.5f * pb[3];
        float x2 = cx + 0.5f * pb[2], y2 = cy + 0.5f * pb[3];
        float lx = fmaxf(x1, tx1), ly = fmaxf(y1, ty1);
        float rx = fminf(x2, tx2), ry = fminf(y2, ty2);
        float wx = fmaxf(rx - lx, 0.0f), wy = fmaxf(ry - ly, 0.0f);
        float inter = wx * wy;
        float area_p = (x2 - x1) * (y2 - y1);
        iou[b] = inter / (area_p + area_t - inter);
    }

    // jnp.argmax picks first max -> box 1 only on strict >
    const bool r = (iou[1] > iou[0]);
    float max_iou = fmaxf(iou[0], iou[1]);

    // responsible-box values via explicit selects
    float pr0 = r ? p[5] : p[0], tr0 = r ? t[5] : t[0];
    float pr1 = r ? p[6] : p[1], tr1 = r ? t[6] : t[1];
    float pr2 = r ? p[7] : p[2], tr2 = r ? t[7] : t[2];
    float pr3 = r ? p[8] : p[3], tr3 = r ? t[8] : t[3];
    float pr4 = r ? p[9] : p[4];

    // class loss: channels 10..29 = vf2 indices 5..14, streamed non-temporal
    float lcls = 0.0f;
#pragma unroll
    for (int i = 5; i < 15; ++i) {
        vf2 a = __builtin_nontemporal_load(p2 + i);
        vf2 b = __builtin_nontemporal_load(t2 + i);
        float d0 = a.x - b.x, d1 = a.y - b.y;
        lcls += d0 * d0 + d1 * d1;
    }

    float obj_l = 0.0f;
    if (obj) {
        float dx = pr0 - tr0, dy = pr1 - tr1;
        float lxy = dx * dx + dy * dy;
        float dw = sqrtf(pr2) - sqrtf(tr2);
        float dh = sqrtf(pr3) - sqrtf(tr3);
        float lwh = dw * dw + dh * dh;
        float dob = pr4 - max_iou;
        float lob = dob * dob;
        obj_l = 5.0f * (lxy + lwh) + lob + lcls;
    }
    float loss = obj_l + 0.5f * noobj_l;

    // wave (64-lane) shuffle reduce, then cross-wave via LDS
    float v = loss;
#pragma unroll
    for (int off = 32; off > 0; off >>= 1)
        v += __shfl_down(v, off, 64);

    __shared__ float red[4];
    const int lane = threadIdx.x & 63;
    const int wid = threadIdx.x >> 6;
    if (lane == 0) red[wid] = v;
    __syncthreads();
    if (threadIdx.x == 0)
        partial[blockIdx.x] = red[0] + red[1] + red[2] + red[3];
}

__global__ __launch_bounds__(256) void yolo_loss_finalize(
    const float* __restrict__ partial, float* __restrict__ out)
{
    double s = 0.0;
    for (int i = threadIdx.x; i < NBLOCKS; i += 256)
        s += (double)partial[i];

    __shared__ double sh[256];
    sh[threadIdx.x] = s;
    __syncthreads();
#pragma unroll
    for (int step = 128; step > 0; step >>= 1) {
        if (threadIdx.x < step) sh[threadIdx.x] += sh[threadIdx.x + step];
        __syncthreads();
    }
    if (threadIdx.x == 0)
        out[0] = (float)(sh[0] / (double)NB);
}

extern "C" void kernel_launch(void* const* d_in, const int* in_sizes, int n_in,
                              void* d_out, int out_size, void* d_ws, size_t ws_size,
                              hipStream_t stream) {
    const float* pred = (const float*)d_in[0];
    const float* target = (const float*)d_in[1];
    float* out = (float*)d_out;
    float* partial = (float*)d_ws;   // NBLOCKS floats = 12.5 KB scratch

    yolo_loss_partial<<<NBLOCKS, 256, 0, stream>>>(pred, target, partial);
    yolo_loss_finalize<<<1, 256, 0, stream>>>(partial, out);
}

// Round 9
// 216.388 us; speedup vs baseline: 1.0554x; 1.0554x over previous
//
#include <hip/hip_runtime.h>

// YOLO-v1 loss, S=14, B=2, C=20, NCH=30, Nb=4096.
// R10: delivered-BW is invariant at ~2.66 TB/s across R3..R9 (direct loads
// are TA-capped at ~1 line-req/cyc/CU by the 120B lane stride; staged R8 was
// 5 waves/CU latency-bound). Discriminating experiment: coalesced + counted
// vmcnt + barrier-free + 2x R8 occupancy. Wave-private 64-cell regions
// (7680B/tensor), staged with HW-VERIFIED widths only: 7x16B + 2x4B per lane
// (12B was the R7 NaN suspect). LDS 15.4KB/block -> ~10 waves/CU.
// If this still lands ~72us, the floor is external -> ROOFLINE.

#define NB 4096
#define NCELL (NB * 14 * 14)            // 802816
#define NCH 30
#define WAVE_CELLS 64
#define NBLOCKS (NCELL / WAVE_CELLS)    // 12544
#define REGION_B (WAVE_CELLS * NCH * 4) // 7680 bytes per tensor

#define GLOBAL_AS __attribute__((address_space(1)))
#define LDS_AS    __attribute__((address_space(3)))

__device__ __forceinline__ void async16(const char* g, char* l) {
    __builtin_amdgcn_global_load_lds((const GLOBAL_AS void*)g, (LDS_AS void*)l,
                                     16, 0, 0);
}
__device__ __forceinline__ void async4(const char* g, char* l) {
    __builtin_amdgcn_global_load_lds((const GLOBAL_AS void*)g, (LDS_AS void*)l,
                                     4, 0, 0);
}

// Per-cell YOLO loss from LDS (stride-30-float rows; ~4-way bank aliasing on
// float2 reads -- LDS is not the critical path, same as R8).
__device__ __forceinline__ float cell_loss_lds(const float* __restrict__ pl,
                                               const float* __restrict__ tl)
{
    const float2* p2 = (const float2*)pl;   // 120B rows: 8B-aligned
    const float2* t2 = (const float2*)tl;

    float p[10], t[10];
#pragma unroll
    for (int i = 0; i < 5; ++i) {
        float2 a = p2[i]; p[2 * i] = a.x; p[2 * i + 1] = a.y;
        float2 b = t2[i]; t[2 * i] = b.x; t[2 * i + 1] = b.y;
    }

    const float t4 = t[4];
    const bool obj = (t4 > 0.0f);

    float dn0 = p[4] - t[4];
    float dn1 = p[9] - t[9];
    float noobj_l = (t4 == 0.0f) ? (dn0 * dn0 + dn1 * dn1) : 0.0f;

    const float invS = 1.0f / 14.0f;
    float tcx = t[0] * invS, tcy = t[1] * invS;
    float tx1 = tcx - 0.5f * t[2], ty1 = tcy - 0.5f * t[3];
    float tx2 = tcx + 0.5f * t[2], ty2 = tcy + 0.5f * t[3];
    float area_t = (tx2 - tx1) * (ty2 - ty1);

    float iou[2];
#pragma unroll
    for (int b = 0; b < 2; ++b) {
        const float* pb = p + 5 * b;
        float cx = pb[0] * invS, cy = pb[1] * invS;
        float x1 = cx - 0.5f * pb[2], y1 = cy - 0.5f * pb[3];
        float x2 = cx + 0.5f * pb[2], y2 = cy + 0.5f * pb[3];
        float lx = fmaxf(x1, tx1), ly = fmaxf(y1, ty1);
        float rx = fminf(x2, tx2), ry = fminf(y2, ty2);
        float wx = fmaxf(rx - lx, 0.0f), wy = fmaxf(ry - ly, 0.0f);
        float inter = wx * wy;
        float area_p = (x2 - x1) * (y2 - y1);
        iou[b] = inter / (area_p + area_t - inter);
    }

    // jnp.argmax picks first max -> box 1 only on strict >
    const bool r = (iou[1] > iou[0]);
    float max_iou = fmaxf(iou[0], iou[1]);

    float pr0 = r ? p[5] : p[0], tr0 = r ? t[5] : t[0];
    float pr1 = r ? p[6] : p[1], tr1 = r ? t[6] : t[1];
    float pr2 = r ? p[7] : p[2], tr2 = r ? t[7] : t[2];
    float pr3 = r ? p[8] : p[3], tr3 = r ? t[8] : t[3];
    float pr4 = r ? p[9] : p[4];

    float lcls = 0.0f;
#pragma unroll
    for (int i = 5; i < 15; ++i) {
        float2 a = p2[i];
        float2 b = t2[i];
        float d0 = a.x - b.x, d1 = a.y - b.y;
        lcls += d0 * d0 + d1 * d1;
    }

    float obj_l = 0.0f;
    if (obj) {
        float dx = pr0 - tr0, dy = pr1 - tr1;
        float lxy = dx * dx + dy * dy;
        float dw = sqrtf(pr2) - sqrtf(tr2);
        float dh = sqrtf(pr3) - sqrtf(tr3);
        float lwh = dw * dw + dh * dh;
        float dob = pr4 - max_iou;
        float lob = dob * dob;
        obj_l = 5.0f * (lxy + lwh) + lob + lcls;
    }
    return obj_l + 0.5f * noobj_l;
}

__global__ __launch_bounds__(64) void yolo_loss_partial(
    const float* __restrict__ pred, const float* __restrict__ target,
    float* __restrict__ partial)
{
    __shared__ __align__(16) float pbuf[REGION_B / 4];   // 7680 B
    __shared__ __align__(16) float tbuf[REGION_B / 4];   // 7680 B

    const int lane = threadIdx.x;                        // block == one wave
    const size_t base = (size_t)blockIdx.x * REGION_B;   // bytes
    const char* gp = (const char*)pred + base;
    const char* gt = (const char*)target + base;
    char* lp = (char*)pbuf;
    char* lt = (char*)tbuf;

    // --- staging: 9 issues/tensor/lane, verified widths only ---
    // 16B rounds r=0..6 cover [0,7168); 4B rounds j=0,1 cover [7168,7680).
    const int o16 = lane * 16;
    const int o4 = 7168 + lane * 4;

    // oldest 8 issues: both tensors' rounds 0..3 -> bytes [0,4096)
#pragma unroll
    for (int r = 0; r < 4; ++r) {
        async16(gp + r * 1024 + o16, lp + r * 1024 + o16);
        async16(gt + r * 1024 + o16, lt + r * 1024 + o16);
    }
    __builtin_amdgcn_sched_barrier(0);   // pin issue order at the phase split
    // remaining 10 issues: rounds 4..6 + two 4B tail rounds, both tensors
#pragma unroll
    for (int r = 4; r < 7; ++r) {
        async16(gp + r * 1024 + o16, lp + r * 1024 + o16);
        async16(gt + r * 1024 + o16, lt + r * 1024 + o16);
    }
    async4(gp + o4, lp + o4);
    async4(gt + o4, lt + o4);
    async4(gp + o4 + 256, lp + o4 + 256);
    async4(gt + o4 + 256, lt + o4 + 256);

    // Phase A: cells 0..31 need bytes [0,3840) -> oldest 8 issues suffice.
    float acc = 0.0f;
    asm volatile("s_waitcnt vmcnt(10)" ::: "memory");
    __builtin_amdgcn_sched_barrier(0);
    if (lane < 32)
        acc = cell_loss_lds(pbuf + lane * NCH, tbuf + lane * NCH);

    // Phase B: cells 32..63 need everything.
    asm volatile("s_waitcnt vmcnt(0)" ::: "memory");
    __builtin_amdgcn_sched_barrier(0);
    if (lane >= 32)
        acc = cell_loss_lds(pbuf + lane * NCH, tbuf + lane * NCH);

    // single-wave shuffle reduce; no barriers in this kernel
    float v = acc;
#pragma unroll
    for (int off = 32; off > 0; off >>= 1)
        v += __shfl_down(v, off, 64);
    if (lane == 0)
        partial[blockIdx.x] = v;
}

__global__ __launch_bounds__(256) void yolo_loss_finalize(
    const float* __restrict__ partial, float* __restrict__ out)
{
    double s = 0.0;
    for (int i = threadIdx.x; i < NBLOCKS; i += 256)
        s += (double)partial[i];

    __shared__ double sh[256];
    sh[threadIdx.x] = s;
    __syncthreads();
#pragma unroll
    for (int step = 128; step > 0; step >>= 1) {
        if (threadIdx.x < step) sh[threadIdx.x] += sh[threadIdx.x + step];
        __syncthreads();
    }
    if (threadIdx.x == 0)
        out[0] = (float)(sh[0] / (double)NB);
}

extern "C" void kernel_launch(void* const* d_in, const int* in_sizes, int n_in,
                              void* d_out, int out_size, void* d_ws, size_t ws_size,
                              hipStream_t stream) {
    const float* pred = (const float*)d_in[0];
    const float* target = (const float*)d_in[1];
    float* out = (float*)d_out;
    float* partial = (float*)d_ws;   // NBLOCKS floats = 50 KB scratch

    yolo_loss_partial<<<NBLOCKS, 64, 0, stream>>>(pred, target, partial);
    yolo_loss_finalize<<<1, 256, 0, stream>>>(partial, out);
}